// Round 13
// baseline (546.518 us; speedup 1.0000x reference)
//
#include <hip/hip_runtime.h>

#define DI __device__ __forceinline__

DI float frcp(float v)  { return __builtin_amdgcn_rcpf(v); }
DI float fsig(float v)  { return frcp(1.0f + __expf(-v)); }
DI float ftanh(float v) { return 1.0f - 2.0f * frcp(__expf(2.0f * v) + 1.0f); }
DI float dot4(float4 a, float4 b) { return a.x*b.x + a.y*b.y + a.z*b.z + a.w*b.w; }

DI unsigned pkrtz(float a, float b) {
    return __builtin_bit_cast(unsigned, __builtin_amdgcn_cvt_pkrtz(a, b));
}

// full-rate mixed-precision MAC: acc += (f32)w.f16[lo/hi] * (f32)z.f16[lo/hi]
DI void fmix_lo(float& acc, unsigned w, unsigned z) {
    asm("v_fma_mix_f32 %0, %1, %2, %0 op_sel:[0,0,0] op_sel_hi:[1,1,0]"
        : "+v"(acc) : "v"(w), "v"(z));
}
DI void fmix_hi(float& acc, unsigned w, unsigned z) {
    asm("v_fma_mix_f32 %0, %1, %2, %0 op_sel:[1,1,0] op_sel_hi:[1,1,0]"
        : "+v"(acc) : "v"(w), "v"(z));
}

// ===================== LSTM scan, 4-way K-split, f16-packed weights + v_fma_mix =====================
// 512 threads. Partial phase: (r0 = tid&127, kq = tid>>7); thread holds 4 gates x 20
// half2 pairs (80 uints, pinned) of K-chunk [40kq,40kq+40) of [x(32)|h(128)]; x/h live
// PACKED f16 in LDS -> 5 ds_read_b128 + 160 v_fma_mix_f32 per step.
// r12 lesson: v_dot2_f32_f16 measured ~3-4x FMA issue cost (VALUBusy arithmetic);
// v_fma_mix_f32 is full-rate and keeps f32 accumulation (slightly MORE accurate).
// Reduce phase: all 512 threads as (rr=tid>>2, gg=tid&3); lane-quad shfl_xor combines
// gates; gg==0 lanes carry h/c in fp32 registers.
template <int MODE>
DI void lstm_scan5(const float* __restrict__ xin,  // [128][32]
                   const float* __restrict__ Wih,  // [512][32]
                   const float* __restrict__ Whh,  // [512][128]
                   const float* __restrict__ bih,
                   const float* __restrict__ bhh,
                   float* __restrict__ rec,        // MODE 0: [128][256] pre-step (h|c)
                   float* __restrict__ outp,       // MODE 1: stride 256
                   float* lds)
{
    const int tid = threadIdx.x;
    const int r0 = tid & 127;
    const int kq = tid >> 7;
    unsigned* xp = (unsigned*)lds;          // [128][16] uints = packed f16 x rows
    unsigned* hp = (unsigned*)lds + 2048;   // 64 uints = packed f16 h
    float* pl = lds + 2112;                 // 2176 : pl[kq*544 + g*136 + r]

    // stage x as packed f16 pairs (pair i = floats 2i,2i+1)
    for (int i = tid; i < 2048; i += 512) {
        const float2 v = *(const float2*)(xin + 2 * i);
        xp[i] = pkrtz(v.x, v.y);
    }
    if (tid < 64) hp[tid] = 0u;

    // weights: 4 gates x 20 packed pairs over K-chunk [40kq, 40kq+40)
    unsigned wpu[4][20];
    #pragma unroll
    for (int g = 0; g < 4; ++g) {
        const int r = g * 128 + r0;
        float4 wt[10];
        if (kq == 0) {
            const float4* pi4 = (const float4*)(Wih + r * 32);
            #pragma unroll
            for (int i = 0; i < 8; ++i) wt[i] = pi4[i];
            const float4* ph4 = (const float4*)(Whh + r * 128);
            wt[8] = ph4[0]; wt[9] = ph4[1];
        } else {
            const float4* ph4 = (const float4*)(Whh + r * 128 + 40 * kq - 32);
            #pragma unroll
            for (int i = 0; i < 10; ++i) wt[i] = ph4[i];
        }
        #pragma unroll
        for (int i = 0; i < 10; ++i) {
            wpu[g][2*i]   = pkrtz(wt[i].x, wt[i].y);
            wpu[g][2*i+1] = pkrtz(wt[i].z, wt[i].w);
        }
    }
    // pin packed weights (asm defs cannot be rematerialized as in-loop reloads)
    #pragma unroll
    for (int g = 0; g < 4; ++g)
        #pragma unroll
        for (int j = 0; j < 20; ++j)
            asm volatile("" : "+v"(wpu[g][j]));

    // reduce-phase mapping
    const int rr = tid >> 2;   // hidden unit 0..127
    const int gg = tid & 3;    // gate
    const float bias = bih[gg * 128 + rr] + bhh[gg * 128 + rr];
    const float nl_a = (gg == 2) ? 2.0f : 1.0f;   // tanh(s) = 2*sig(2s) - 1
    const float nl_b = (gg == 2) ? -1.0f : 0.0f;
    float hreg = 0.f, creg = 0.f;
    __syncthreads();

    for (int t = 0; t < 128; ++t) {
        // ---- partial phase: 5 packed uint4 of z, 160 v_fma_mix ----
        uint4 z0, z1, z2, z3, ze;
        if (kq == 0) {
            const uint4* x4 = (const uint4*)(xp + t * 16);
            z0 = x4[0]; z1 = x4[1]; z2 = x4[2]; z3 = x4[3];
            ze = *(const uint4*)hp;
        } else {
            const uint4* h4 = (const uint4*)(hp + 20 * kq - 16);
            z0 = h4[0]; z1 = h4[1]; z2 = h4[2]; z3 = h4[3]; ze = h4[4];
        }
        float a0 = 0.f, a1 = 0.f, a2 = 0.f, a3 = 0.f;
        #define DG(J, U) { const unsigned zz = (U); \
            fmix_lo(a0, wpu[0][J], zz); fmix_hi(a0, wpu[0][J], zz); \
            fmix_lo(a1, wpu[1][J], zz); fmix_hi(a1, wpu[1][J], zz); \
            fmix_lo(a2, wpu[2][J], zz); fmix_hi(a2, wpu[2][J], zz); \
            fmix_lo(a3, wpu[3][J], zz); fmix_hi(a3, wpu[3][J], zz); }
        DG(0,  z0.x) DG(1,  z0.y) DG(2,  z0.z) DG(3,  z0.w)
        DG(4,  z1.x) DG(5,  z1.y) DG(6,  z1.z) DG(7,  z1.w)
        DG(8,  z2.x) DG(9,  z2.y) DG(10, z2.z) DG(11, z2.w)
        DG(12, z3.x) DG(13, z3.y) DG(14, z3.z) DG(15, z3.w)
        DG(16, ze.x) DG(17, ze.y) DG(18, ze.z) DG(19, ze.w)
        #undef DG
        pl[kq * 544 +       r0] = a0;
        pl[kq * 544 + 136 + r0] = a1;
        pl[kq * 544 + 272 + r0] = a2;
        pl[kq * 544 + 408 + r0] = a3;
        __syncthreads();

        // ---- reduce + nonlinearity + state update (all 512 threads) ----
        float s = bias + pl[gg * 136 + rr]        + pl[544 + gg * 136 + rr]
                       + pl[1088 + gg * 136 + rr] + pl[1632 + gg * 136 + rr];
        float sg  = frcp(1.0f + __expf(-(nl_a * s)));
        float val = nl_a * sg + nl_b;              // i,f,o: sig(s); g: tanh(s)
        float v1 = __shfl_xor(val, 1);
        float v2 = __shfl_xor(val, 2);
        float v3 = __shfl_xor(val, 3);
        // on gg==0 lanes: val=i, v1=f, v2=g, v3=o (garbage elsewhere, unused)
        float cn = v1 * creg + val * v2;
        float hn = v3 * ftanh(cn);
        float hn_hi = __shfl_down(hn, 4);          // h[rr+1] (lane+4 is also a gg==0 lane)
        if (gg == 0) {
            if (MODE == 0) {
                rec[t * 256 + rr]       = hreg;    // pre-step state
                rec[t * 256 + 128 + rr] = creg;
            }
            creg = cn; hreg = hn;
            if (MODE == 1) outp[t * 256 + rr] = hn;
        }
        if ((tid & 7) == 0) hp[rr >> 1] = pkrtz(hn, hn_hi);
        __syncthreads();
    }
}

// ===================== self-attention, 512 threads, 4 t per iteration =====================
DI void selfatt_body(const float* __restrict__ x, const float* __restrict__ Wg,
                     const float* __restrict__ bg, const float* __restrict__ Wa,
                     const float* __restrict__ ba, float* __restrict__ sa,
                     int b, float* s)
{
    float* xl  = s;                // 128*33
    float* Wgl = s + 4224;
    float* WaT = s + 8448;
    float* bgl = s + 12672;        // 128
    float* bal = s + 12800;        // 32
    float* gl  = s + 12832;        // 4*128
    float* pp  = s + 13344;        // 4*4*32

    const int tid = threadIdx.x;
    for (int i = tid; i < 4096; i += 512) {
        int r = i >> 5, n = i & 31;
        xl[r * 33 + n]  = x[b * 4096 + i];
        Wgl[r * 33 + n] = Wg[i];
        WaT[(i & 127) * 33 + (i >> 7)] = Wa[i];
    }
    if (tid < 128) bgl[tid] = bg[tid];
    else if (tid < 160) bal[tid - 128] = ba[tid - 128];
    __syncthreads();

    const int tl = tid >> 7;          // 0..3
    for (int it = 0; it < 32; ++it) {
        {   const int m = tid & 127;
            const int t = it * 4 + tl;
            float acc = bgl[m];
            #pragma unroll
            for (int n = 0; n < 32; ++n) acc += xl[t * 33 + n] * Wgl[m * 33 + n];
            gl[tl * 128 + m] = ftanh(acc);
        }
        __syncthreads();
        {   const int n = tid & 31, c = (tid >> 5) & 3;
            float acc = 0.f;
            #pragma unroll
            for (int j = 0; j < 32; ++j) {
                int m = c * 32 + j;
                acc += gl[tl * 128 + m] * WaT[m * 33 + n];
            }
            pp[(tl * 4 + c) * 32 + n] = acc;
        }
        __syncthreads();
        if (tid < 128) {
            const int tl2 = tid >> 5, n = tid & 31;
            const int t = it * 4 + tl2;
            float sv = pp[(tl2 * 4 + 0) * 32 + n] + pp[(tl2 * 4 + 1) * 32 + n]
                     + pp[(tl2 * 4 + 2) * 32 + n] + pp[(tl2 * 4 + 3) * 32 + n] + bal[n];
            sa[b * 4096 + t * 32 + n] = fsig(sv) * xl[t * 33 + n];
        }
        __syncthreads();
    }
}

// k1: blocks 0..127 -> LSTM0 (record rec); 128..255 -> self-attention
__global__ __launch_bounds__(512)
void k1_lstm0_sa(const float* __restrict__ x,
                 const float* __restrict__ Wih0, const float* __restrict__ Whh0,
                 const float* __restrict__ bih0, const float* __restrict__ bhh0,
                 const float* __restrict__ Wg, const float* __restrict__ bg,
                 const float* __restrict__ Wa, const float* __restrict__ ba,
                 float* __restrict__ rec, float* __restrict__ sa)
{
    __shared__ float smem[13856];
    const int blk = blockIdx.x;
    if (blk < 128) {
        lstm_scan5<0>(x + blk * 4096, Wih0, Whh0, bih0, bhh0,
                      rec + blk * 32768, nullptr, smem);
    } else {
        selfatt_body(x, Wg, bg, Wa, ba, sa, blk - 128, smem);
    }
}

// k3: blocks 0..127 -> LSTM1 (ia -> out cols 0..127); 128..255 -> LSTM2 (sa -> cols 128..255)
__global__ __launch_bounds__(512)
void k3_lstm12(const float* __restrict__ ia, const float* __restrict__ sa,
               const float* __restrict__ Wih1, const float* __restrict__ Whh1,
               const float* __restrict__ bih1, const float* __restrict__ bhh1,
               const float* __restrict__ Wih2, const float* __restrict__ Whh2,
               const float* __restrict__ bih2, const float* __restrict__ bhh2,
               float* __restrict__ out)
{
    __shared__ float smem[4288];
    const int blk = blockIdx.x;
    if (blk < 128) {
        lstm_scan5<1>(ia + blk * 4096, Wih1, Whh1, bih1, bhh1,
                      nullptr, out + blk * 32768, smem);
    } else {
        const int b = blk - 128;
        lstm_scan5<1>(sa + b * 4096, Wih2, Whh2, bih2, bhh2,
                      nullptr, out + b * 32768 + 128, smem);
    }
}

// ===================== kP (separate-output variant): w2[b][t][m] = 2*(We @ [h;c]) =====================
// 256 blocks = (b, half); reads rec (read-only), writes w2 -> no aliasing, full GPU.
__global__ __launch_bounds__(512, 1)
void kP_w2_sep(const float* __restrict__ We, const float* __restrict__ rec,
               float* __restrict__ w2)
{
    __shared__ float smem[12544];          // hsB 32*260 | wbuf 32*132
    float* hsB  = smem;
    float* wbuf = smem + 8320;
    const int tid = threadIdx.x;
    const int b  = blockIdx.x >> 1;
    const int hh = blockIdx.x & 1;
    const int m = tid >> 2, q = tid & 3;

    float4 wer[16];
    {
        const float4* p = (const float4*)(We + m * 256 + q * 64);
        #pragma unroll
        for (int i = 0; i < 16; ++i) wer[i] = p[i];
    }
    #pragma unroll
    for (int i = 0; i < 16; i += 4) {
        asm volatile("" : "+v"(wer[i].x), "+v"(wer[i].y), "+v"(wer[i].z), "+v"(wer[i].w),
                          "+v"(wer[i+1].x), "+v"(wer[i+1].y), "+v"(wer[i+1].z), "+v"(wer[i+1].w),
                          "+v"(wer[i+2].x), "+v"(wer[i+2].y), "+v"(wer[i+2].z), "+v"(wer[i+2].w),
                          "+v"(wer[i+3].x), "+v"(wer[i+3].y), "+v"(wer[i+3].z), "+v"(wer[i+3].w));
    }

    for (int t2 = 0; t2 < 2; ++t2) {
        const int tb = hh * 2 + t2;
        __syncthreads();
        for (int i = tid; i < 8192; i += 512)
            hsB[(i >> 8) * 260 + (i & 255)] = rec[(long)b * 32768 + (tb * 32 + (i >> 8)) * 256 + (i & 255)];
        __syncthreads();
        for (int tl = 0; tl < 32; ++tl) {
            const float4* h4 = (const float4*)(hsB + tl * 260 + q * 64);
            float acc = 0.f;
            #pragma unroll
            for (int i = 0; i < 16; ++i) acc += dot4(wer[i], h4[i]);
            acc += __shfl_xor(acc, 1);
            acc += __shfl_xor(acc, 2);
            if (q == 0) wbuf[tl * 132 + m] = acc;
        }
        __syncthreads();
        for (int i = tid; i < 4096; i += 512)
            w2[(long)b * 16384 + tb * 4096 + i] = 2.0f * wbuf[(i >> 7) * 132 + (i & 127)];
    }
}

// kP fallback (r10-proven): in-place into rec, 128 blocks, tb-sequential flush safety.
__global__ __launch_bounds__(512, 1)
void kP_w2_inplace(const float* __restrict__ We, float* __restrict__ rec)
{
    __shared__ float smem[12544];
    float* hsB  = smem;
    float* wbuf = smem + 8320;
    const int tid = threadIdx.x;
    const int b = blockIdx.x;
    const int m = tid >> 2, q = tid & 3;

    float4 wer[16];
    {
        const float4* p = (const float4*)(We + m * 256 + q * 64);
        #pragma unroll
        for (int i = 0; i < 16; ++i) wer[i] = p[i];
    }
    #pragma unroll
    for (int i = 0; i < 16; i += 4) {
        asm volatile("" : "+v"(wer[i].x), "+v"(wer[i].y), "+v"(wer[i].z), "+v"(wer[i].w),
                          "+v"(wer[i+1].x), "+v"(wer[i+1].y), "+v"(wer[i+1].z), "+v"(wer[i+1].w),
                          "+v"(wer[i+2].x), "+v"(wer[i+2].y), "+v"(wer[i+2].z), "+v"(wer[i+2].w),
                          "+v"(wer[i+3].x), "+v"(wer[i+3].y), "+v"(wer[i+3].z), "+v"(wer[i+3].w));
    }

    for (int tb = 0; tb < 4; ++tb) {
        __syncthreads();
        for (int i = tid; i < 8192; i += 512)
            hsB[(i >> 8) * 260 + (i & 255)] = rec[(long)b * 32768 + (tb * 32 + (i >> 8)) * 256 + (i & 255)];
        __syncthreads();
        for (int tl = 0; tl < 32; ++tl) {
            const float4* h4 = (const float4*)(hsB + tl * 260 + q * 64);
            float acc = 0.f;
            #pragma unroll
            for (int i = 0; i < 16; ++i) acc += dot4(wer[i], h4[i]);
            acc += __shfl_xor(acc, 1);
            acc += __shfl_xor(acc, 2);
            if (q == 0) wbuf[tl * 132 + m] = acc;
        }
        __syncthreads();
        for (int i = tid; i < 4096; i += 512)
            rec[(long)b * 32768 + tb * 4096 + i] = 2.0f * wbuf[(i >> 7) * 132 + (i & 127)];
    }
}

// ===================== kB: input attention =====================
__global__ __launch_bounds__(512, 2)
void kB_attn(const float* __restrict__ x,    // [128][128][32]
             const float* __restrict__ Ue,   // [128][32]
             const float* __restrict__ Ve,   // [128]
             const float* __restrict__ w2g,  // [b][t][128] *2, stride bstr per b
             long bstr,
             float* __restrict__ ia)         // [128][128][32]
{
    __shared__ float xl[4608];     // [tau][36]
    __shared__ float wl[4224];     // [32 t][132]
    __shared__ float uxc[4224];    // [32 m][132 tau]
    __shared__ float UeAv[4608];   // Uel [128][36] during e-phase; av [32 t][128] after
    __shared__ float vel[128];     // 2*Ve
    __shared__ float sinv[32];
    __shared__ float iap[576];     // [16][36]

    const int tid = threadIdx.x;
    const int b  = blockIdx.x >> 2;
    const int tc = blockIdx.x & 3;

    for (int i = tid; i < 4096; i += 512) {
        xl[(i >> 5) * 36 + (i & 31)]   = x[b * 4096 + i];
        UeAv[(i >> 5) * 36 + (i & 31)] = Ue[i];
        wl[(i >> 7) * 132 + (i & 127)] = w2g[(long)b * bstr + (tc * 32 + (i >> 7)) * 128 + (i & 127)];
    }
    if (tid < 128) vel[tid] = 2.0f * Ve[tid];
    __syncthreads();

    const int ts = tid & 127, mg = tid >> 7;   // staging: row ts, m-octet mg
    float4 xr[8];
    {
        const float4* xp = (const float4*)(xl + ts * 36);
        #pragma unroll
        for (int i = 0; i < 8; ++i) xr[i] = xp[i];
    }
    float VeTot = 0.f;
    for (int i = 0; i < 128; ++i) VeTot += vel[i];
    VeTot *= 0.5f;

    const int tp = tid >> 5, tg = tid & 31;
    const int t0 = 2 * tp, t1 = t0 + 1;
    float s0[4] = {0.f, 0.f, 0.f, 0.f};
    float s1[4] = {0.f, 0.f, 0.f, 0.f};

    for (int mc = 0; mc < 4; ++mc) {
        #pragma unroll
        for (int j = 0; j < 8; ++j) {
            const int ml = mg * 8 + j;
            const float4* u4 = (const float4*)(UeAv + (mc * 32 + ml) * 36);
            float acc = 0.f;
            #pragma unroll
            for (int i = 0; i < 8; ++i) acc += dot4(xr[i], u4[i]);
            uxc[ml * 132 + ts] = 2.0f * acc;
        }
        __syncthreads();
        #pragma unroll 8
        for (int ml = 0; ml < 32; ++ml) {
            const int m = mc * 32 + ml;
            const float vm = vel[m];
            const float w0 = wl[t0 * 132 + m];
            const float w1 = wl[t1 * 132 + m];
            const float4 u4 = *(const float4*)(uxc + ml * 132 + 4 * tg);
            s0[0] += vm * frcp(__expf(u4.x + w0) + 1.0f);
            s0[1] += vm * frcp(__expf(u4.y + w0) + 1.0f);
            s0[2] += vm * frcp(__expf(u4.z + w0) + 1.0f);
            s0[3] += vm * frcp(__expf(u4.w + w0) + 1.0f);
            s1[0] += vm * frcp(__expf(u4.x + w1) + 1.0f);
            s1[1] += vm * frcp(__expf(u4.y + w1) + 1.0f);
            s1[2] += vm * frcp(__expf(u4.z + w1) + 1.0f);
            s1[3] += vm * frcp(__expf(u4.w + w1) + 1.0f);
        }
        __syncthreads();
    }

    float e0[4], e1[4];
    #pragma unroll
    for (int j = 0; j < 4; ++j) { e0[j] = VeTot - s0[j]; e1[j] = VeTot - s1[j]; }
    float M0 = fmaxf(fmaxf(e0[0], e0[1]), fmaxf(e0[2], e0[3]));
    float M1 = fmaxf(fmaxf(e1[0], e1[1]), fmaxf(e1[2], e1[3]));
    #pragma unroll
    for (int o = 1; o < 32; o <<= 1) {
        M0 = fmaxf(M0, __shfl_xor(M0, o));
        M1 = fmaxf(M1, __shfl_xor(M1, o));
    }
    float a00 = __expf(e0[0] - M0), a01 = __expf(e0[1] - M0);
    float a02 = __expf(e0[2] - M0), a03 = __expf(e0[3] - M0);
    float a10 = __expf(e1[0] - M1), a11 = __expf(e1[1] - M1);
    float a12 = __expf(e1[2] - M1), a13 = __expf(e1[3] - M1);
    float S0 = a00 + a01 + a02 + a03;
    float S1 = a10 + a11 + a12 + a13;
    #pragma unroll
    for (int o = 1; o < 32; o <<= 1) {
        S0 += __shfl_xor(S0, o);
        S1 += __shfl_xor(S1, o);
    }
    float* av = UeAv;   // Ue no longer needed
    *(float4*)(av + t0 * 128 + 4 * tg) = make_float4(a00, a01, a02, a03);
    *(float4*)(av + t1 * 128 + 4 * tg) = make_float4(a10, a11, a12, a13);
    if (tg == 0) { sinv[t0] = frcp(S0); sinv[t1] = frcp(S1); }
    __syncthreads();

    const int gph = tid >> 5, n = tid & 31;
    for (int tl = 0; tl < 32; ++tl) {
        float acc = 0.f;
        #pragma unroll
        for (int j = 0; j < 8; ++j)
            acc += av[tl * 128 + gph * 8 + j] * xl[(gph * 8 + j) * 36 + n];
        iap[gph * 36 + n] = acc;
        __syncthreads();
        if (tid < 32) {
            float s = 0.f;
            #pragma unroll
            for (int g = 0; g < 16; ++g) s += iap[g * 36 + tid];
            ia[((long)(b * 128 + tc * 32 + tl)) * 32 + tid] = s * sinv[tl];
        }
        __syncthreads();
    }
}

extern "C" void kernel_launch(void* const* d_in, const int* in_sizes, int n_in,
                              void* d_out, int out_size, void* d_ws, size_t ws_size,
                              hipStream_t stream)
{
    const float* x    = (const float*)d_in[0];
    const float* Wih0 = (const float*)d_in[1];
    const float* Whh0 = (const float*)d_in[2];
    const float* bih0 = (const float*)d_in[3];
    const float* bhh0 = (const float*)d_in[4];
    const float* We   = (const float*)d_in[5];
    const float* Ue   = (const float*)d_in[6];
    const float* Ve   = (const float*)d_in[7];
    const float* Wg   = (const float*)d_in[8];
    const float* bg   = (const float*)d_in[9];
    const float* Wa   = (const float*)d_in[10];
    const float* ba   = (const float*)d_in[11];
    const float* Wih1 = (const float*)d_in[12];
    const float* Whh1 = (const float*)d_in[13];
    const float* bih1 = (const float*)d_in[14];
    const float* bhh1 = (const float*)d_in[15];
    const float* Wih2 = (const float*)d_in[16];
    const float* Whh2 = (const float*)d_in[17];
    const float* bih2 = (const float*)d_in[18];
    const float* bhh2 = (const float*)d_in[19];

    float* out = (float*)d_out;
    float* ws  = (float*)d_ws;
    // workspace (floats): sa 524288 | rec 4194304 | ia 524288 | [w2 2097152 if room]
    float* sa  = ws;
    float* rec = ws + 524288;
    float* iaw = ws + 4718592;
    float* w2  = ws + 5242880;
    const bool sep = ws_size >= (size_t)7340032 * 4;   // 28 MiB

    k1_lstm0_sa<<<256, 512, 0, stream>>>(x, Wih0, Whh0, bih0, bhh0,
                                         Wg, bg, Wa, ba, rec, sa);
    if (sep) {
        kP_w2_sep<<<256, 512, 0, stream>>>(We, rec, w2);
        kB_attn<<<512, 512, 0, stream>>>(x, Ue, Ve, w2, 16384L, iaw);
    } else {
        kP_w2_inplace<<<128, 512, 0, stream>>>(We, rec);
        kB_attn<<<512, 512, 0, stream>>>(x, Ue, Ve, rec, 32768L, iaw);
    }
    k3_lstm12<<<256, 512, 0, stream>>>(iaw, sa, Wih1, Whh1, bih1, bhh1,
                                       Wih2, Whh2, bih2, bhh2, out);
}

// Round 15
// 447.911 us; speedup vs baseline: 1.2201x; 1.2201x over previous
//
#include <hip/hip_runtime.h>

#define DI __device__ __forceinline__

typedef _Float16 h2v __attribute__((ext_vector_type(2)));

DI float frcp(float v)  { return __builtin_amdgcn_rcpf(v); }
DI float fexp2(float v) { return __builtin_amdgcn_exp2f(v); }   // raw v_exp_f32 (2^x); __exp2f collides with glibc math.h
DI float fsig(float v)  { return frcp(1.0f + __expf(-v)); }
DI float ftanh(float v) { return 1.0f - 2.0f * frcp(__expf(2.0f * v) + 1.0f); }
DI float dot4(float4 a, float4 b) { return a.x*b.x + a.y*b.y + a.z*b.z + a.w*b.w; }

DI h2v u2h(unsigned u) { return __builtin_bit_cast(h2v, u); }
DI unsigned pkrtz(float a, float b) {
    return __builtin_bit_cast(unsigned, __builtin_amdgcn_cvt_pkrtz(a, b));
}

DI float fdot2w(h2v a, h2v b, float c) {
#if __has_builtin(__builtin_amdgcn_fdot2)
    return __builtin_amdgcn_fdot2(a, b, c, false);
#else
    return c + (float)a.x * (float)b.x + (float)a.y * (float)b.y;
#endif
}

#define TWO_LOG2E 2.8853900817779268f

// ===================== LSTM scan, 4-way K-split, f16-packed weights + dot2 =====================
// r12-proven structure (148 us/pass). r13 lesson: v_fma_mix_f32 is ALSO quarter-rate
// (~6 cyc) -> 160 insts lose to dot2's 80 (~7 cyc). dot2 is the best packed-f16 MAC here.
template <int MODE>
DI void lstm_scan4(const float* __restrict__ xin,  // [128][32]
                   const float* __restrict__ Wih,  // [512][32]
                   const float* __restrict__ Whh,  // [512][128]
                   const float* __restrict__ bih,
                   const float* __restrict__ bhh,
                   float* __restrict__ rec,        // MODE 0: [128][256] pre-step (h|c)
                   float* __restrict__ outp,       // MODE 1: stride 256
                   float* lds)
{
    const int tid = threadIdx.x;
    const int r0 = tid & 127;
    const int kq = tid >> 7;
    unsigned* xp = (unsigned*)lds;          // [128][16] uints = packed f16 x rows
    unsigned* hp = (unsigned*)lds + 2048;   // 64 uints = packed f16 h
    float* pl = lds + 2112;                 // 2176 : pl[kq*544 + g*136 + r]

    for (int i = tid; i < 2048; i += 512) {
        const float2 v = *(const float2*)(xin + 2 * i);
        xp[i] = pkrtz(v.x, v.y);
    }
    if (tid < 64) hp[tid] = 0u;

    // weights: 4 gates x 20 packed pairs over K-chunk [40kq, 40kq+40)
    unsigned wpu[4][20];
    #pragma unroll
    for (int g = 0; g < 4; ++g) {
        const int r = g * 128 + r0;
        float4 wt[10];
        if (kq == 0) {
            const float4* pi4 = (const float4*)(Wih + r * 32);
            #pragma unroll
            for (int i = 0; i < 8; ++i) wt[i] = pi4[i];
            const float4* ph4 = (const float4*)(Whh + r * 128);
            wt[8] = ph4[0]; wt[9] = ph4[1];
        } else {
            const float4* ph4 = (const float4*)(Whh + r * 128 + 40 * kq - 32);
            #pragma unroll
            for (int i = 0; i < 10; ++i) wt[i] = ph4[i];
        }
        #pragma unroll
        for (int i = 0; i < 10; ++i) {
            wpu[g][2*i]   = pkrtz(wt[i].x, wt[i].y);
            wpu[g][2*i+1] = pkrtz(wt[i].z, wt[i].w);
        }
    }
    // pin packed weights (asm defs cannot be rematerialized as in-loop reloads)
    #pragma unroll
    for (int g = 0; g < 4; ++g)
        #pragma unroll
        for (int j = 0; j < 20; ++j)
            asm volatile("" : "+v"(wpu[g][j]));

    const int rr = tid >> 2;   // hidden unit 0..127
    const int gg = tid & 3;    // gate
    const float bias = bih[gg * 128 + rr] + bhh[gg * 128 + rr];
    const float nl_a = (gg == 2) ? 2.0f : 1.0f;   // tanh(s) = 2*sig(2s) - 1
    const float nl_b = (gg == 2) ? -1.0f : 0.0f;
    float hreg = 0.f, creg = 0.f;
    __syncthreads();

    for (int t = 0; t < 128; ++t) {
        uint4 z0, z1, z2, z3, ze;
        if (kq == 0) {
            const uint4* x4 = (const uint4*)(xp + t * 16);
            z0 = x4[0]; z1 = x4[1]; z2 = x4[2]; z3 = x4[3];
            ze = *(const uint4*)hp;
        } else {
            const uint4* h4 = (const uint4*)(hp + 20 * kq - 16);
            z0 = h4[0]; z1 = h4[1]; z2 = h4[2]; z3 = h4[3]; ze = h4[4];
        }
        float a0 = 0.f, a1 = 0.f, a2 = 0.f, a3 = 0.f;
        #define DG(J, U) { const h2v zz = u2h(U); \
            a0 = fdot2w(u2h(wpu[0][J]), zz, a0); \
            a1 = fdot2w(u2h(wpu[1][J]), zz, a1); \
            a2 = fdot2w(u2h(wpu[2][J]), zz, a2); \
            a3 = fdot2w(u2h(wpu[3][J]), zz, a3); }
        DG(0,  z0.x) DG(1,  z0.y) DG(2,  z0.z) DG(3,  z0.w)
        DG(4,  z1.x) DG(5,  z1.y) DG(6,  z1.z) DG(7,  z1.w)
        DG(8,  z2.x) DG(9,  z2.y) DG(10, z2.z) DG(11, z2.w)
        DG(12, z3.x) DG(13, z3.y) DG(14, z3.z) DG(15, z3.w)
        DG(16, ze.x) DG(17, ze.y) DG(18, ze.z) DG(19, ze.w)
        #undef DG
        pl[kq * 544 +       r0] = a0;
        pl[kq * 544 + 136 + r0] = a1;
        pl[kq * 544 + 272 + r0] = a2;
        pl[kq * 544 + 408 + r0] = a3;
        __syncthreads();

        float s = bias + pl[gg * 136 + rr]        + pl[544 + gg * 136 + rr]
                       + pl[1088 + gg * 136 + rr] + pl[1632 + gg * 136 + rr];
        float sg  = frcp(1.0f + __expf(-(nl_a * s)));
        float val = nl_a * sg + nl_b;              // i,f,o: sig(s); g: tanh(s)
        float v1 = __shfl_xor(val, 1);
        float v2 = __shfl_xor(val, 2);
        float v3 = __shfl_xor(val, 3);
        float cn = v1 * creg + val * v2;
        float hn = v3 * ftanh(cn);
        float hn_hi = __shfl_down(hn, 4);
        if (gg == 0) {
            if (MODE == 0) {
                rec[t * 256 + rr]       = hreg;
                rec[t * 256 + 128 + rr] = creg;
            }
            creg = cn; hreg = hn;
            if (MODE == 1) outp[t * 256 + rr] = hn;
        }
        if ((tid & 7) == 0) hp[rr >> 1] = pkrtz(hn, hn_hi);
        __syncthreads();
    }
}

// ===================== self-attention, 512 threads, 4 t per iteration =====================
DI void selfatt_body(const float* __restrict__ x, const float* __restrict__ Wg,
                     const float* __restrict__ bg, const float* __restrict__ Wa,
                     const float* __restrict__ ba, float* __restrict__ sa,
                     int b, float* s)
{
    float* xl  = s;                // 128*33
    float* Wgl = s + 4224;
    float* WaT = s + 8448;
    float* bgl = s + 12672;        // 128
    float* bal = s + 12800;        // 32
    float* gl  = s + 12832;        // 4*128
    float* pp  = s + 13344;        // 4*4*32

    const int tid = threadIdx.x;
    for (int i = tid; i < 4096; i += 512) {
        int r = i >> 5, n = i & 31;
        xl[r * 33 + n]  = x[b * 4096 + i];
        Wgl[r * 33 + n] = Wg[i];
        WaT[(i & 127) * 33 + (i >> 7)] = Wa[i];
    }
    if (tid < 128) bgl[tid] = bg[tid];
    else if (tid < 160) bal[tid - 128] = ba[tid - 128];
    __syncthreads();

    const int tl = tid >> 7;          // 0..3
    for (int it = 0; it < 32; ++it) {
        {   const int m = tid & 127;
            const int t = it * 4 + tl;
            float acc = bgl[m];
            #pragma unroll
            for (int n = 0; n < 32; ++n) acc += xl[t * 33 + n] * Wgl[m * 33 + n];
            gl[tl * 128 + m] = ftanh(acc);
        }
        __syncthreads();
        {   const int n = tid & 31, c = (tid >> 5) & 3;
            float acc = 0.f;
            #pragma unroll
            for (int j = 0; j < 32; ++j) {
                int m = c * 32 + j;
                acc += gl[tl * 128 + m] * WaT[m * 33 + n];
            }
            pp[(tl * 4 + c) * 32 + n] = acc;
        }
        __syncthreads();
        if (tid < 128) {
            const int tl2 = tid >> 5, n = tid & 31;
            const int t = it * 4 + tl2;
            float sv = pp[(tl2 * 4 + 0) * 32 + n] + pp[(tl2 * 4 + 1) * 32 + n]
                     + pp[(tl2 * 4 + 2) * 32 + n] + pp[(tl2 * 4 + 3) * 32 + n] + bal[n];
            sa[b * 4096 + t * 32 + n] = fsig(sv) * xl[t * 33 + n];
        }
        __syncthreads();
    }
}

// k1: blocks 0..127 -> LSTM0 (record rec); 128..255 -> self-attention
__global__ __launch_bounds__(512)
void k1_lstm0_sa(const float* __restrict__ x,
                 const float* __restrict__ Wih0, const float* __restrict__ Whh0,
                 const float* __restrict__ bih0, const float* __restrict__ bhh0,
                 const float* __restrict__ Wg, const float* __restrict__ bg,
                 const float* __restrict__ Wa, const float* __restrict__ ba,
                 float* __restrict__ rec, float* __restrict__ sa)
{
    __shared__ float smem[13856];
    const int blk = blockIdx.x;
    if (blk < 128) {
        lstm_scan4<0>(x + blk * 4096, Wih0, Whh0, bih0, bhh0,
                      rec + blk * 32768, nullptr, smem);
    } else {
        selfatt_body(x, Wg, bg, Wa, ba, sa, blk - 128, smem);
    }
}

// k3: blocks 0..127 -> LSTM1 (ia -> out cols 0..127); 128..255 -> LSTM2 (sa -> cols 128..255)
__global__ __launch_bounds__(512)
void k3_lstm12(const float* __restrict__ ia, const float* __restrict__ sa,
               const float* __restrict__ Wih1, const float* __restrict__ Whh1,
               const float* __restrict__ bih1, const float* __restrict__ bhh1,
               const float* __restrict__ Wih2, const float* __restrict__ Whh2,
               const float* __restrict__ bih2, const float* __restrict__ bhh2,
               float* __restrict__ out)
{
    __shared__ float smem[4288];
    const int blk = blockIdx.x;
    if (blk < 128) {
        lstm_scan4<1>(ia + blk * 4096, Wih1, Whh1, bih1, bhh1,
                      nullptr, out + blk * 32768, smem);
    } else {
        const int b = blk - 128;
        lstm_scan4<1>(sa + b * 4096, Wih2, Whh2, bih2, bhh2,
                      nullptr, out + b * 32768 + 128, smem);
    }
}

// ===================== kP (separate-output): w2[b][t][m] = 2*log2e*(We @ [h;c]) =====================
// 256 blocks = (b, half); reads rec (read-only), writes w2 pre-scaled for exp2 in kB.
__global__ __launch_bounds__(512, 1)
void kP_w2_sep(const float* __restrict__ We, const float* __restrict__ rec,
               float* __restrict__ w2)
{
    __shared__ float smem[12544];          // hsB 32*260 | wbuf 32*132
    float* hsB  = smem;
    float* wbuf = smem + 8320;
    const int tid = threadIdx.x;
    const int b  = blockIdx.x >> 1;
    const int hh = blockIdx.x & 1;
    const int m = tid >> 2, q = tid & 3;

    float4 wer[16];
    {
        const float4* p = (const float4*)(We + m * 256 + q * 64);
        #pragma unroll
        for (int i = 0; i < 16; ++i) wer[i] = p[i];
    }
    #pragma unroll
    for (int i = 0; i < 16; i += 4) {
        asm volatile("" : "+v"(wer[i].x), "+v"(wer[i].y), "+v"(wer[i].z), "+v"(wer[i].w),
                          "+v"(wer[i+1].x), "+v"(wer[i+1].y), "+v"(wer[i+1].z), "+v"(wer[i+1].w),
                          "+v"(wer[i+2].x), "+v"(wer[i+2].y), "+v"(wer[i+2].z), "+v"(wer[i+2].w),
                          "+v"(wer[i+3].x), "+v"(wer[i+3].y), "+v"(wer[i+3].z), "+v"(wer[i+3].w));
    }

    for (int t2 = 0; t2 < 2; ++t2) {
        const int tb = hh * 2 + t2;
        __syncthreads();
        for (int i = tid; i < 8192; i += 512)
            hsB[(i >> 8) * 260 + (i & 255)] = rec[(long)b * 32768 + (tb * 32 + (i >> 8)) * 256 + (i & 255)];
        __syncthreads();
        for (int tl = 0; tl < 32; ++tl) {
            const float4* h4 = (const float4*)(hsB + tl * 260 + q * 64);
            float acc = 0.f;
            #pragma unroll
            for (int i = 0; i < 16; ++i) acc += dot4(wer[i], h4[i]);
            acc += __shfl_xor(acc, 1);
            acc += __shfl_xor(acc, 2);
            if (q == 0) wbuf[tl * 132 + m] = acc;
        }
        __syncthreads();
        for (int i = tid; i < 4096; i += 512)
            w2[(long)b * 16384 + tb * 4096 + i] = TWO_LOG2E * wbuf[(i >> 7) * 132 + (i & 127)];
    }
}

// kP fallback: in-place into rec, 128 blocks, tb-sequential flush safety.
__global__ __launch_bounds__(512, 1)
void kP_w2_inplace(const float* __restrict__ We, float* __restrict__ rec)
{
    __shared__ float smem[12544];
    float* hsB  = smem;
    float* wbuf = smem + 8320;
    const int tid = threadIdx.x;
    const int b = blockIdx.x;
    const int m = tid >> 2, q = tid & 3;

    float4 wer[16];
    {
        const float4* p = (const float4*)(We + m * 256 + q * 64);
        #pragma unroll
        for (int i = 0; i < 16; ++i) wer[i] = p[i];
    }
    #pragma unroll
    for (int i = 0; i < 16; i += 4) {
        asm volatile("" : "+v"(wer[i].x), "+v"(wer[i].y), "+v"(wer[i].z), "+v"(wer[i].w),
                          "+v"(wer[i+1].x), "+v"(wer[i+1].y), "+v"(wer[i+1].z), "+v"(wer[i+1].w),
                          "+v"(wer[i+2].x), "+v"(wer[i+2].y), "+v"(wer[i+2].z), "+v"(wer[i+2].w),
                          "+v"(wer[i+3].x), "+v"(wer[i+3].y), "+v"(wer[i+3].z), "+v"(wer[i+3].w));
    }

    for (int tb = 0; tb < 4; ++tb) {
        __syncthreads();
        for (int i = tid; i < 8192; i += 512)
            hsB[(i >> 8) * 260 + (i & 255)] = rec[(long)b * 32768 + (tb * 32 + (i >> 8)) * 256 + (i & 255)];
        __syncthreads();
        for (int tl = 0; tl < 32; ++tl) {
            const float4* h4 = (const float4*)(hsB + tl * 260 + q * 64);
            float acc = 0.f;
            #pragma unroll
            for (int i = 0; i < 16; ++i) acc += dot4(wer[i], h4[i]);
            acc += __shfl_xor(acc, 1);
            acc += __shfl_xor(acc, 2);
            if (q == 0) wbuf[tl * 132 + m] = acc;
        }
        __syncthreads();
        for (int i = tid; i < 4096; i += 512)
            rec[(long)b * 32768 + tb * 4096 + i] = TWO_LOG2E * wbuf[(i >> 7) * 132 + (i & 127)];
    }
}

// ===================== kB: input attention =====================
// e-loop operates in exp2 domain: uxc/wl hold 2*log2e*(ux/w) so each element is
// add + v_exp + add + rcp + fma (the pre-exp v_mul is folded into the scales).
__global__ __launch_bounds__(512, 2)
void kB_attn(const float* __restrict__ x,    // [128][128][32]
             const float* __restrict__ Ue,   // [128][32]
             const float* __restrict__ Ve,   // [128]
             const float* __restrict__ w2g,  // [b][t][128] pre-scaled, stride bstr per b
             long bstr,
             float* __restrict__ ia)         // [128][128][32]
{
    __shared__ float xl[4608];     // [tau][36]
    __shared__ float wl[4224];     // [32 t][132]
    __shared__ float uxc[4224];    // [32 m][132 tau]
    __shared__ float UeAv[4608];   // Uel [128][36] during e-phase; av [32 t][128] after
    __shared__ float vel[128];     // 2*Ve
    __shared__ float sinv[32];
    __shared__ float iap[576];     // [16][36]

    const int tid = threadIdx.x;
    const int b  = blockIdx.x >> 2;
    const int tc = blockIdx.x & 3;

    for (int i = tid; i < 4096; i += 512) {
        xl[(i >> 5) * 36 + (i & 31)]   = x[b * 4096 + i];
        UeAv[(i >> 5) * 36 + (i & 31)] = Ue[i];
        wl[(i >> 7) * 132 + (i & 127)] = w2g[(long)b * bstr + (tc * 32 + (i >> 7)) * 128 + (i & 127)];
    }
    if (tid < 128) vel[tid] = 2.0f * Ve[tid];
    __syncthreads();

    const int ts = tid & 127, mg = tid >> 7;   // staging: row ts, m-octet mg
    float4 xr[8];
    {
        const float4* xp = (const float4*)(xl + ts * 36);
        #pragma unroll
        for (int i = 0; i < 8; ++i) xr[i] = xp[i];
    }
    float VeTot = 0.f;
    for (int i = 0; i < 128; ++i) VeTot += vel[i];
    VeTot *= 0.5f;

    const int tp = tid >> 5, tg = tid & 31;
    const int t0 = 2 * tp, t1 = t0 + 1;
    float s0[4] = {0.f, 0.f, 0.f, 0.f};
    float s1[4] = {0.f, 0.f, 0.f, 0.f};

    for (int mc = 0; mc < 4; ++mc) {
        #pragma unroll
        for (int j = 0; j < 8; ++j) {
            const int ml = mg * 8 + j;
            const float4* u4 = (const float4*)(UeAv + (mc * 32 + ml) * 36);
            float acc = 0.f;
            #pragma unroll
            for (int i = 0; i < 8; ++i) acc += dot4(xr[i], u4[i]);
            uxc[ml * 132 + ts] = TWO_LOG2E * acc;
        }
        __syncthreads();
        #pragma unroll 8
        for (int ml = 0; ml < 32; ++ml) {
            const int m = mc * 32 + ml;
            const float vm = vel[m];
            const float w0 = wl[t0 * 132 + m];
            const float w1 = wl[t1 * 132 + m];
            const float4 u4 = *(const float4*)(uxc + ml * 132 + 4 * tg);
            s0[0] += vm * frcp(fexp2(u4.x + w0) + 1.0f);
            s0[1] += vm * frcp(fexp2(u4.y + w0) + 1.0f);
            s0[2] += vm * frcp(fexp2(u4.z + w0) + 1.0f);
            s0[3] += vm * frcp(fexp2(u4.w + w0) + 1.0f);
            s1[0] += vm * frcp(fexp2(u4.x + w1) + 1.0f);
            s1[1] += vm * frcp(fexp2(u4.y + w1) + 1.0f);
            s1[2] += vm * frcp(fexp2(u4.z + w1) + 1.0f);
            s1[3] += vm * frcp(fexp2(u4.w + w1) + 1.0f);
        }
        __syncthreads();
    }

    float e0[4], e1[4];
    #pragma unroll
    for (int j = 0; j < 4; ++j) { e0[j] = VeTot - s0[j]; e1[j] = VeTot - s1[j]; }
    float M0 = fmaxf(fmaxf(e0[0], e0[1]), fmaxf(e0[2], e0[3]));
    float M1 = fmaxf(fmaxf(e1[0], e1[1]), fmaxf(e1[2], e1[3]));
    #pragma unroll
    for (int o = 1; o < 32; o <<= 1) {
        M0 = fmaxf(M0, __shfl_xor(M0, o));
        M1 = fmaxf(M1, __shfl_xor(M1, o));
    }
    float a00 = __expf(e0[0] - M0), a01 = __expf(e0[1] - M0);
    float a02 = __expf(e0[2] - M0), a03 = __expf(e0[3] - M0);
    float a10 = __expf(e1[0] - M1), a11 = __expf(e1[1] - M1);
    float a12 = __expf(e1[2] - M1), a13 = __expf(e1[3] - M1);
    float S0 = a00 + a01 + a02 + a03;
    float S1 = a10 + a11 + a12 + a13;
    #pragma unroll
    for (int o = 1; o < 32; o <<= 1) {
        S0 += __shfl_xor(S0, o);
        S1 += __shfl_xor(S1, o);
    }
    float* av = UeAv;   // Ue no longer needed
    *(float4*)(av + t0 * 128 + 4 * tg) = make_float4(a00, a01, a02, a03);
    *(float4*)(av + t1 * 128 + 4 * tg) = make_float4(a10, a11, a12, a13);
    if (tg == 0) { sinv[t0] = frcp(S0); sinv[t1] = frcp(S1); }
    __syncthreads();

    const int gph = tid >> 5, n = tid & 31;
    for (int tl = 0; tl < 32; ++tl) {
        float acc = 0.f;
        #pragma unroll
        for (int j = 0; j < 8; ++j)
            acc += av[tl * 128 + gph * 8 + j] * xl[(gph * 8 + j) * 36 + n];
        iap[gph * 36 + n] = acc;
        __syncthreads();
        if (tid < 32) {
            float s = 0.f;
            #pragma unroll
            for (int g = 0; g < 16; ++g) s += iap[g * 36 + tid];
            ia[((long)(b * 128 + tc * 32 + tl)) * 32 + tid] = s * sinv[tl];
        }
        __syncthreads();
    }
}

extern "C" void kernel_launch(void* const* d_in, const int* in_sizes, int n_in,
                              void* d_out, int out_size, void* d_ws, size_t ws_size,
                              hipStream_t stream)
{
    const float* x    = (const float*)d_in[0];
    const float* Wih0 = (const float*)d_in[1];
    const float* Whh0 = (const float*)d_in[2];
    const float* bih0 = (const float*)d_in[3];
    const float* bhh0 = (const float*)d_in[4];
    const float* We   = (const float*)d_in[5];
    const float* Ue   = (const float*)d_in[6];
    const float* Ve   = (const float*)d_in[7];
    const float* Wg   = (const float*)d_in[8];
    const float* bg   = (const float*)d_in[9];
    const float* Wa   = (const float*)d_in[10];
    const float* ba   = (const float*)d_in[11];
    const float* Wih1 = (const float*)d_in[12];
    const float* Whh1 = (const float*)d_in[13];
    const float* bih1 = (const float*)d_in[14];
    const float* bhh1 = (const float*)d_in[15];
    const float* Wih2 = (const float*)d_in[16];
    const float* Whh2 = (const float*)d_in[17];
    const float* bih2 = (const float*)d_in[18];
    const float* bhh2 = (const float*)d_in[19];

    float* out = (float*)d_out;
    float* ws  = (float*)d_ws;
    // workspace (floats): sa 524288 | rec 4194304 | ia 524288 | [w2 2097152 if room]
    float* sa  = ws;
    float* rec = ws + 524288;
    float* iaw = ws + 4718592;
    float* w2  = ws + 5242880;
    const bool sep = ws_size >= (size_t)7340032 * 4;   // 28 MiB

    k1_lstm0_sa<<<256, 512, 0, stream>>>(x, Wih0, Whh0, bih0, bhh0,
                                         Wg, bg, Wa, ba, rec, sa);
    if (sep) {
        kP_w2_sep<<<256, 512, 0, stream>>>(We, rec, w2);
        kB_attn<<<512, 512, 0, stream>>>(x, Ue, Ve, w2, 16384L, iaw);
    } else {
        kP_w2_inplace<<<128, 512, 0, stream>>>(We, rec);
        kB_attn<<<512, 512, 0, stream>>>(x, Ue, Ve, rec, 32768L, iaw);
    }
    k3_lstm12<<<256, 512, 0, stream>>>(iaw, sa, Wih1, Whh1, bih1, bhh1,
                                       Wih2, Whh2, bih2, bhh2, out);
}